// Round 4
// baseline (932.799 us; speedup 1.0000x reference)
//
#include <hip/hip_runtime.h>
#include <math.h>

#define EMB 128
#define HEADS 8
#define SEQ 200
#define BATCH 128
#define FFD 512
#define CHUNK 32          // batches per chunk
#define NCHUNK 4

typedef __attribute__((ext_vector_type(8))) short bf16x8;
typedef __attribute__((ext_vector_type(4))) float f32x4;

__device__ __forceinline__ unsigned short f2b(float f) {
  union { float f; unsigned int u; } v; v.f = f;
  unsigned int u = v.u;
  return (unsigned short)((u + 0x7fffu + ((u >> 16) & 1u)) >> 16);
}

// ---------------- prep: x + pos_emb -> fp32 residual + bf16 copy ----------------
__global__ __launch_bounds__(256) void prep_kernel(const float* __restrict__ x,
    const float* __restrict__ pos, float* __restrict__ xpos,
    unsigned short* __restrict__ xb) {
  int idx = blockIdx.x * 256 + threadIdx.x;     // 819200 threads, 4 floats each
  int base = idx * 4;
  int tok = base >> 7;
  int t = tok % SEQ;
  int e = base & 127;
  float4 xv = *(const float4*)(x + base);
  float4 pv = *(const float4*)(pos + t * EMB + e);
  float4 r;
  r.x = xv.x + pv.x; r.y = xv.y + pv.y; r.z = xv.z + pv.z; r.w = xv.w + pv.w;
  *(float4*)(xpos + base) = r;
  ushort4 o;
  o.x = f2b(r.x); o.y = f2b(r.y); o.z = f2b(r.z); o.w = f2b(r.w);
  *(ushort4*)(xb + base) = o;
}

// ---------------- weight fp32 -> bf16, transposed to (N,K) ----------------
__global__ __launch_bounds__(256) void wconv_kernel(const float* __restrict__ src,
    unsigned short* __restrict__ dst, int K, int N) {
  int idx = blockIdx.x * 256 + threadIdx.x;
  if (idx >= K * N) return;
  int k = idx / N, n = idx - k * N;
  dst[n * K + k] = f2b(src[idx]);
}

// ---------------- generic MFMA GEMM: C = A(MxK,row) * Bt(NxK,row)^T ----------------
// mode 0: out bf16 at (b_local,h,t,e) layout   (b_local = m/SEQ)
// mode 1: out bf16 at v-transposed layout (b_local,h,e,t)
// mode 2: outf fp32 = C + bias[n] + resid[m*128+n]   (N must be 128)
// mode 3: outb bf16 = gelu(C + bias[n]) at (m, n) with row stride 512
__global__ __launch_bounds__(256) void gemm_kernel(
    const unsigned short* __restrict__ A, const unsigned short* __restrict__ Bt,
    int K, int mode,
    const float* __restrict__ bias, const float* __restrict__ resid,
    unsigned short* __restrict__ outb, float* __restrict__ outf) {
  __shared__ unsigned short As[128][72];
  __shared__ unsigned short Bs[128][72];
  const int tid = threadIdx.x;
  const int bm = blockIdx.x * 128;
  const int bn = blockIdx.y * 128;
  const int wave = tid >> 6, lane = tid & 63;
  const int wm = (wave >> 1) * 64, wn = (wave & 1) * 64;
  const int row16 = lane & 15, quad = lane >> 4;

  const f32x4 zf = {0.f, 0.f, 0.f, 0.f};
  f32x4 acc[4][4];
#pragma unroll
  for (int i = 0; i < 4; i++)
#pragma unroll
    for (int j = 0; j < 4; j++) acc[i][j] = zf;

  for (int k0 = 0; k0 < K; k0 += 64) {
    for (int i = tid; i < 1024; i += 256) {
      int r = i >> 3, g = (i & 7) * 8;
      *(bf16x8*)&As[r][g] = *(const bf16x8*)&A[(size_t)(bm + r) * K + k0 + g];
    }
    for (int i = tid; i < 1024; i += 256) {
      int r = i >> 3, g = (i & 7) * 8;
      *(bf16x8*)&Bs[r][g] = *(const bf16x8*)&Bt[(size_t)(bn + r) * K + k0 + g];
    }
    __syncthreads();
#pragma unroll
    for (int ks = 0; ks < 2; ks++) {
      bf16x8 af[4], bfr[4];
#pragma unroll
      for (int i = 0; i < 4; i++)
        af[i] = *(const bf16x8*)&As[wm + i * 16 + row16][ks * 32 + quad * 8];
#pragma unroll
      for (int j = 0; j < 4; j++)
        bfr[j] = *(const bf16x8*)&Bs[wn + j * 16 + row16][ks * 32 + quad * 8];
#pragma unroll
      for (int i = 0; i < 4; i++)
#pragma unroll
        for (int j = 0; j < 4; j++)
          acc[i][j] = __builtin_amdgcn_mfma_f32_16x16x32_bf16(af[i], bfr[j], acc[i][j], 0, 0, 0);
    }
    __syncthreads();
  }

#pragma unroll
  for (int i = 0; i < 4; i++) {
#pragma unroll
    for (int j = 0; j < 4; j++) {
#pragma unroll
      for (int r = 0; r < 4; r++) {
        int m = bm + wm + i * 16 + quad * 4 + r;
        int n = bn + wn + j * 16 + row16;
        float c = acc[i][j][r];
        if (mode == 0) {
          int bb = m / SEQ, t = m - bb * SEQ;
          int hh = n >> 7, e = n & 127;
          outb[(size_t)((bb * HEADS + hh) * SEQ + t) * EMB + e] = f2b(c);
        } else if (mode == 1) {
          int bb = m / SEQ, t = m - bb * SEQ;
          int hh = n >> 7, e = n & 127;
          outb[(size_t)((bb * HEADS + hh) * EMB + e) * SEQ + t] = f2b(c);
        } else if (mode == 2) {
          float v = c + bias[n] + resid[(size_t)m * EMB + n];
          outf[(size_t)m * EMB + n] = v;
        } else {
          float v = c + bias[n];
          v = 0.5f * v * (1.0f + erff(v * 0.70710678118f));
          outb[(size_t)m * FFD + n] = f2b(v);
        }
      }
    }
  }
}

// ---------------- attention v2: one block per (b_local,h); K/V direct from L2 ----------------
// Static LDS only (47.5 KB): Qs + Ps + mask. 3 blocks/CU occupancy.
__global__ __launch_bounds__(256) void attn_kernel(
    const unsigned short* __restrict__ q, const unsigned short* __restrict__ k,
    const unsigned short* __restrict__ vt, const int* __restrict__ masks,
    unsigned short* __restrict__ att, int bc0) {
  __shared__ unsigned short Qs[64][136];
  __shared__ unsigned short Ps[64][232];
  __shared__ unsigned short mk[208];

  const int bh = blockIdx.x;          // 0..255 within chunk
  const int bl = bh >> 3, h = bh & 7; // local batch, head
  const int bg = bc0 + bl;            // global batch
  const int b0 = bg >> 3, ag = bg & 7;
  const int tid = threadIdx.x;
  const int wave = tid >> 6, lane = tid & 63;
  const int row16 = lane & 15, quad = lane >> 4;
  const int q0 = wave * 16;

  const bf16x8 zv = {0, 0, 0, 0, 0, 0, 0, 0};
  const f32x4 zf = {0.f, 0.f, 0.f, 0.f};

  for (int t = tid; t < 208; t += 256)
    mk[t] = (t < SEQ) ? (unsigned short)(masks[(b0 * SEQ + t) * 8 + ag] != 0)
                      : (unsigned short)0;
  if (tid < 128) {  // zero P pad columns 208..223 (once; never overwritten)
    int r = tid >> 1, gcol = 208 + (tid & 1) * 8;
    *(bf16x8*)&Ps[r][gcol] = zv;
  }

  const unsigned short* qg = q + (size_t)bh * SEQ * EMB;
  const unsigned short* kg = k + (size_t)bh * SEQ * EMB;
  const unsigned short* vg = vt + (size_t)bh * EMB * SEQ;
  const float sc = 0.08838834764831845f;  // 1/sqrt(128) -> q*k scaled by 1/128 total
  unsigned short* ab = att + (size_t)bl * SEQ * (HEADS * EMB) + h * EMB;

  for (int qt = 0; qt < 4; qt++) {
    for (int i = tid; i < 64 * 16; i += 256) {
      int r = i >> 4, g = (i & 15) * 8;
      int gr = qt * 64 + r;
      bf16x8 v = (gr < SEQ) ? *(const bf16x8*)&qg[gr * EMB + g] : zv;
      *(bf16x8*)&Qs[r][g] = v;
    }
    __syncthreads();

    // S = (Q/s)(K/s)^T : 13 key-fragments of 16; K read direct (L2-resident)
    f32x4 s[13];
#pragma unroll
    for (int kf = 0; kf < 13; kf++) s[kf] = zf;
#pragma unroll
    for (int e0 = 0; e0 < 4; e0++) {
      bf16x8 aq = *(const bf16x8*)&Qs[q0 + row16][e0 * 32 + quad * 8];
#pragma unroll
      for (int kf = 0; kf < 13; kf++) {
        int kr = kf * 16 + row16;
        kr = (kr < SEQ) ? kr : 0;  // clamp: OOB key rows masked later; avoids NaN/garbage
        bf16x8 bk = *(const bf16x8*)&kg[kr * EMB + e0 * 32 + quad * 8];
        s[kf] = __builtin_amdgcn_mfma_f32_16x16x32_bf16(aq, bk, s[kf], 0, 0, 0);
      }
    }

    float kadd[13], kzero[13];
#pragma unroll
    for (int kf = 0; kf < 13; kf++) {
      bool mv = mk[kf * 16 + row16] != 0;
      kadd[kf] = mv ? 0.0f : -1e30f;
      kzero[kf] = mv ? 1.0f : 0.0f;
    }

#pragma unroll
    for (int r = 0; r < 4; r++) {
      int prow = q0 + quad * 4 + r;
      int grow = qt * 64 + prow;
      float qm = (grow < SEQ) ? (mk[grow] ? 1.0f : 0.0f) : 0.0f;
      float sv[13];
      float mx = -1e30f;
#pragma unroll
      for (int kf = 0; kf < 13; kf++) {
        float v = s[kf][r] * sc + kadd[kf];
        sv[kf] = v;
        mx = fmaxf(mx, v);
      }
#pragma unroll
      for (int d = 1; d < 16; d <<= 1) mx = fmaxf(mx, __shfl_xor(mx, d));
      float sum = 0.f;
#pragma unroll
      for (int kf = 0; kf < 13; kf++) {
        float e = __expf(sv[kf] - mx);
        sv[kf] = e;
        sum += e;
      }
#pragma unroll
      for (int d = 1; d < 16; d <<= 1) sum += __shfl_xor(sum, d);
      float inv = qm / sum;
#pragma unroll
      for (int kf = 0; kf < 13; kf++)
        Ps[prow][kf * 16 + row16] = f2b(sv[kf] * inv * kzero[kf]);
    }

    // O = P V ; V^T (e,t) read direct; t-groups >= SEQ zeroed (P cols there are 0)
    f32x4 o[8];
#pragma unroll
    for (int n = 0; n < 8; n++) o[n] = zf;
#pragma unroll
    for (int ks = 0; ks < 7; ks++) {
      bf16x8 ap = *(const bf16x8*)&Ps[q0 + row16][ks * 32 + quad * 8];
      int t0 = ks * 32 + quad * 8;
#pragma unroll
      for (int n = 0; n < 8; n++) {
        int er = n * 16 + row16;
        bf16x8 bv = (t0 < SEQ) ? *(const bf16x8*)&vg[er * SEQ + t0] : zv;
        o[n] = __builtin_amdgcn_mfma_f32_16x16x32_bf16(ap, bv, o[n], 0, 0, 0);
      }
    }

#pragma unroll
    for (int n = 0; n < 8; n++) {
#pragma unroll
      for (int r = 0; r < 4; r++) {
        int grow = qt * 64 + q0 + quad * 4 + r;
        if (grow < SEQ)
          ab[(size_t)grow * (HEADS * EMB) + n * 16 + row16] = f2b(o[n][r]);
      }
    }
    __syncthreads();
  }
}

// ---------------- LayerNorm over last dim 128; one wave per token ----------------
__global__ __launch_bounds__(256) void ln_kernel(const float* __restrict__ in,
    const float* __restrict__ w, const float* __restrict__ b,
    float* __restrict__ outf, unsigned short* __restrict__ outb) {
  int wave = threadIdx.x >> 6, lane = threadIdx.x & 63;
  int tokidx = blockIdx.x * 4 + wave;
  const float* row = in + (size_t)tokidx * EMB;
  float2 v = *(const float2*)(row + lane * 2);
  float sum = v.x + v.y;
  float sq = v.x * v.x + v.y * v.y;
#pragma unroll
  for (int d = 1; d < 64; d <<= 1) {
    sum += __shfl_xor(sum, d);
    sq += __shfl_xor(sq, d);
  }
  float mean = sum * (1.0f / 128.0f);
  float var = sq * (1.0f / 128.0f) - mean * mean;
  float rstd = rsqrtf(var + 1e-5f);
  float2 wv = *(const float2*)(w + lane * 2);
  float2 bv = *(const float2*)(b + lane * 2);
  float2 ov;
  ov.x = (v.x - mean) * rstd * wv.x + bv.x;
  ov.y = (v.y - mean) * rstd * wv.y + bv.y;
  *(float2*)(outf + (size_t)tokidx * EMB + lane * 2) = ov;
  if (outb) {
    outb[(size_t)tokidx * EMB + lane * 2] = f2b(ov.x);
    outb[(size_t)tokidx * EMB + lane * 2 + 1] = f2b(ov.y);
  }
}

extern "C" void kernel_launch(void* const* d_in, const int* in_sizes, int n_in,
                              void* d_out, int out_size, void* d_ws, size_t ws_size,
                              hipStream_t stream) {
  const float* x    = (const float*)d_in[0];
  const float* pos  = (const float*)d_in[1];
  const float* Wq   = (const float*)d_in[2];
  const float* Wk   = (const float*)d_in[3];
  const float* Wv   = (const float*)d_in[4];
  const float* Wu   = (const float*)d_in[5];
  const float* bu   = (const float*)d_in[6];
  const float* ln1w = (const float*)d_in[7];
  const float* ln1b = (const float*)d_in[8];
  const float* W1   = (const float*)d_in[9];
  const float* b1   = (const float*)d_in[10];
  const float* W2   = (const float*)d_in[11];
  const float* b2   = (const float*)d_in[12];
  const float* ln2w = (const float*)d_in[13];
  const float* ln2b = (const float*)d_in[14];
  const int* masks  = (const int*)d_in[15];
  float* out = (float*)d_out;
  (void)in_sizes; (void)n_in; (void)out_size; (void)ws_size;

  // ---- workspace layout (high-water 86,507,520 B = 86.5 MB) ----
  char* ws = (char*)d_ws;
  unsigned short* wqt = (unsigned short*)(ws + 0);         // 262,144
  unsigned short* wkt = (unsigned short*)(ws + 262144);
  unsigned short* wvt = (unsigned short*)(ws + 524288);
  unsigned short* wut = (unsigned short*)(ws + 786432);
  unsigned short* w1t = (unsigned short*)(ws + 1048576);
  unsigned short* w2t = (unsigned short*)(ws + 1179648);   // -> 1,310,720
  float* xpos         = (float*)(ws + 1310720);            // 13,107,200 -> 14,417,920
  unsigned short* xb  = (unsigned short*)(ws + 14417920);  //  6,553,600 -> 20,971,520
  float* t1           = (float*)(ws + 20971520);           // 13,107,200 -> 34,078,720
  unsigned short* qc  = (unsigned short*)(ws + 34078720);  // 13,107,200 -> 47,185,920
  unsigned short* kc  = (unsigned short*)(ws + 47185920);  // 13,107,200 -> 60,293,120
  unsigned short* vc  = (unsigned short*)(ws + 60293120);  // 13,107,200 -> 73,400,320
  unsigned short* attc= (unsigned short*)(ws + 73400320);  // 13,107,200 -> 86,507,520
  // post-attention (qc/kc/vc/attc dead): alias into 34,078,720..86,507,520
  float* yf          = (float*)(ws + 34078720);            // 13,107,200 -> 47,185,920
  unsigned short* yb = (unsigned short*)(ws + 47185920);   //  6,553,600 -> 53,739,520
  unsigned short* g  = (unsigned short*)(ws + 53739520);   // 26,214,400 -> 79,953,920

  prep_kernel<<<3200, 256, 0, stream>>>(x, pos, xpos, xb);

  wconv_kernel<<<512, 256, 0, stream>>>(Wq, wqt, 128, 1024);
  wconv_kernel<<<512, 256, 0, stream>>>(Wk, wkt, 128, 1024);
  wconv_kernel<<<512, 256, 0, stream>>>(Wv, wvt, 128, 1024);
  wconv_kernel<<<512, 256, 0, stream>>>(Wu, wut, 1024, 128);
  wconv_kernel<<<256, 256, 0, stream>>>(W1, w1t, 128, 512);
  wconv_kernel<<<256, 256, 0, stream>>>(W2, w2t, 512, 128);

  for (int c = 0; c < NCHUNK; c++) {
    const unsigned short* xbc = xb + (size_t)c * CHUNK * SEQ * EMB;
    gemm_kernel<<<dim3(50, 8), 256, 0, stream>>>(xbc, wqt, 128, 0, nullptr, nullptr, qc, nullptr);
    gemm_kernel<<<dim3(50, 8), 256, 0, stream>>>(xbc, wkt, 128, 0, nullptr, nullptr, kc, nullptr);
    gemm_kernel<<<dim3(50, 8), 256, 0, stream>>>(xbc, wvt, 128, 1, nullptr, nullptr, vc, nullptr);
    attn_kernel<<<256, 256, 0, stream>>>(qc, kc, vc, masks, attc, c * CHUNK);
    gemm_kernel<<<dim3(50, 1), 256, 0, stream>>>(attc, wut, 1024, 2, bu,
        xpos + (size_t)c * CHUNK * SEQ * EMB, nullptr, t1 + (size_t)c * CHUNK * SEQ * EMB);
  }

  ln_kernel<<<6400, 256, 0, stream>>>(t1, ln1w, ln1b, yf, yb);
  gemm_kernel<<<dim3(200, 4), 256, 0, stream>>>(yb, w1t, 128, 3, b1, nullptr, g, nullptr);
  gemm_kernel<<<dim3(200, 1), 256, 0, stream>>>(g, w2t, 512, 2, b2, yf, nullptr, t1);
  ln_kernel<<<6400, 256, 0, stream>>>(t1, ln2w, ln2b, out, nullptr);
}

// Round 10
// 503.844 us; speedup vs baseline: 1.8514x; 1.8514x over previous
//
#include <hip/hip_runtime.h>
#include <math.h>

#define EMB 128
#define HEADS 8
#define SEQ 200
#define BATCH 128
#define FFD 512
#define CHUNK 32          // batches per chunk
#define NCHUNK 4

typedef __attribute__((ext_vector_type(8))) short bf16x8;
typedef __attribute__((ext_vector_type(4))) float f32x4;

__device__ __forceinline__ unsigned short f2b(float f) {
  union { float f; unsigned int u; } v; v.f = f;
  unsigned int u = v.u;
  return (unsigned short)((u + 0x7fffu + ((u >> 16) & 1u)) >> 16);
}

// ---------------- prep: x + pos_emb -> fp32 residual + bf16 copy ----------------
__global__ __launch_bounds__(256) void prep_kernel(const float* __restrict__ x,
    const float* __restrict__ pos, float* __restrict__ xpos,
    unsigned short* __restrict__ xb) {
  int idx = blockIdx.x * 256 + threadIdx.x;
  int base = idx * 4;
  int tok = base >> 7;
  int t = tok % SEQ;
  int e = base & 127;
  float4 xv = *(const float4*)(x + base);
  float4 pv = *(const float4*)(pos + t * EMB + e);
  float4 r;
  r.x = xv.x + pv.x; r.y = xv.y + pv.y; r.z = xv.z + pv.z; r.w = xv.w + pv.w;
  *(float4*)(xpos + base) = r;
  ushort4 o;
  o.x = f2b(r.x); o.y = f2b(r.y); o.z = f2b(r.z); o.w = f2b(r.w);
  *(ushort4*)(xb + base) = o;
}

// ---------------- all six weights fp32 -> bf16 transposed, one dispatch ----------------
// wqkv rows: [0,1024)=Wq^T, [1024,2048)=Wk^T, [2048,3072)=Wv^T (row=n, col=k, K=128)
__global__ __launch_bounds__(256) void wconv_all(
    const float* __restrict__ Wq, const float* __restrict__ Wk,
    const float* __restrict__ Wv, const float* __restrict__ Wu,
    const float* __restrict__ W1, const float* __restrict__ W2,
    unsigned short* __restrict__ wqkv, unsigned short* __restrict__ wut,
    unsigned short* __restrict__ w1t, unsigned short* __restrict__ w2t) {
  int idx = blockIdx.x * 256 + threadIdx.x;   // 0 .. 655359
  if (idx < 393216) {                          // Wq/Wk/Wv: 3 x (128x1024)
    int t = idx / 131072, r = idx - t * 131072;  // r = k*1024 + n
    int k = r >> 10, n = r & 1023;
    const float* W = (t == 0) ? Wq : (t == 1) ? Wk : Wv;
    wqkv[(size_t)(t * 1024 + n) * 128 + k] = f2b(W[r]);
  } else if (idx < 524288) {                   // Wu: 1024x128, r = k*128 + n
    int r = idx - 393216; int k = r >> 7, n = r & 127;
    wut[(size_t)n * 1024 + k] = f2b(Wu[r]);
  } else if (idx < 589824) {                   // W1: 128x512, r = k*512 + n
    int r = idx - 524288; int k = r >> 9, n = r & 511;
    w1t[(size_t)n * 128 + k] = f2b(W1[r]);
  } else {                                     // W2: 512x128, r = k*128 + n
    int r = idx - 589824; int k = r >> 7, n = r & 127;
    w2t[(size_t)n * 512 + k] = f2b(W2[r]);
  }
}

// ---------------- merged QKV GEMM per chunk: grid (50, 24), K=128 ----------------
// blockIdx.y: tensor = y>>3 (0=Q,1=K,2=V), head h = y&7.
// Q/K out (b_local,h,t,e); V out transposed (b_local,h,e,t).
__global__ __launch_bounds__(256) void gemm_qkv(
    const unsigned short* __restrict__ A, const unsigned short* __restrict__ Bt,
    unsigned short* __restrict__ qc, unsigned short* __restrict__ kc,
    unsigned short* __restrict__ vc) {
  __shared__ unsigned short As[128][72];
  __shared__ unsigned short Bs[128][72];
  const int K = 128;
  const int tid = threadIdx.x;
  const int bm = blockIdx.x * 128;
  const int bn = blockIdx.y * 128;
  const int wave = tid >> 6, lane = tid & 63;
  const int wm = (wave >> 1) * 64, wn = (wave & 1) * 64;
  const int row16 = lane & 15, quad = lane >> 4;

  const f32x4 zf = {0.f, 0.f, 0.f, 0.f};
  f32x4 acc[4][4];
#pragma unroll
  for (int i = 0; i < 4; i++)
#pragma unroll
    for (int j = 0; j < 4; j++) acc[i][j] = zf;

  for (int k0 = 0; k0 < K; k0 += 64) {
    for (int i = tid; i < 1024; i += 256) {
      int r = i >> 3, g = (i & 7) * 8;
      *(bf16x8*)&As[r][g] = *(const bf16x8*)&A[(size_t)(bm + r) * K + k0 + g];
    }
    for (int i = tid; i < 1024; i += 256) {
      int r = i >> 3, g = (i & 7) * 8;
      *(bf16x8*)&Bs[r][g] = *(const bf16x8*)&Bt[(size_t)(bn + r) * K + k0 + g];
    }
    __syncthreads();
#pragma unroll
    for (int ks = 0; ks < 2; ks++) {
      bf16x8 af[4], bfr[4];
#pragma unroll
      for (int i = 0; i < 4; i++)
        af[i] = *(const bf16x8*)&As[wm + i * 16 + row16][ks * 32 + quad * 8];
#pragma unroll
      for (int j = 0; j < 4; j++)
        bfr[j] = *(const bf16x8*)&Bs[wn + j * 16 + row16][ks * 32 + quad * 8];
#pragma unroll
      for (int i = 0; i < 4; i++)
#pragma unroll
        for (int j = 0; j < 4; j++)
          acc[i][j] = __builtin_amdgcn_mfma_f32_16x16x32_bf16(af[i], bfr[j], acc[i][j], 0, 0, 0);
    }
    __syncthreads();
  }

  const int tensor = blockIdx.y >> 3, h = blockIdx.y & 7;
  unsigned short* outp = (tensor == 0) ? qc : (tensor == 1) ? kc : vc;
#pragma unroll
  for (int i = 0; i < 4; i++) {
#pragma unroll
    for (int j = 0; j < 4; j++) {
#pragma unroll
      for (int r = 0; r < 4; r++) {
        int m = bm + wm + i * 16 + quad * 4 + r;
        int n = wn + j * 16 + row16;          // e within head
        float c = acc[i][j][r];
        int bb = m / SEQ, t = m - bb * SEQ;
        if (tensor < 2)
          outp[(size_t)((bb * HEADS + h) * SEQ + t) * EMB + n] = f2b(c);
        else
          outp[(size_t)((bb * HEADS + h) * EMB + n) * SEQ + t] = f2b(c);
      }
    }
  }
}

// ---------------- FF1 GEMM: out bf16 = gelu(C + bias), grid (200,4), K=128 ----------------
__global__ __launch_bounds__(256) void gemm_ff1(
    const unsigned short* __restrict__ A, const unsigned short* __restrict__ Bt,
    const float* __restrict__ bias, unsigned short* __restrict__ outb) {
  __shared__ unsigned short As[128][72];
  __shared__ unsigned short Bs[128][72];
  const int K = 128;
  const int tid = threadIdx.x;
  const int bm = blockIdx.x * 128;
  const int bn = blockIdx.y * 128;
  const int wave = tid >> 6, lane = tid & 63;
  const int wm = (wave >> 1) * 64, wn = (wave & 1) * 64;
  const int row16 = lane & 15, quad = lane >> 4;

  const f32x4 zf = {0.f, 0.f, 0.f, 0.f};
  f32x4 acc[4][4];
#pragma unroll
  for (int i = 0; i < 4; i++)
#pragma unroll
    for (int j = 0; j < 4; j++) acc[i][j] = zf;

  for (int k0 = 0; k0 < K; k0 += 64) {
    for (int i = tid; i < 1024; i += 256) {
      int r = i >> 3, g = (i & 7) * 8;
      *(bf16x8*)&As[r][g] = *(const bf16x8*)&A[(size_t)(bm + r) * K + k0 + g];
    }
    for (int i = tid; i < 1024; i += 256) {
      int r = i >> 3, g = (i & 7) * 8;
      *(bf16x8*)&Bs[r][g] = *(const bf16x8*)&Bt[(size_t)(bn + r) * K + k0 + g];
    }
    __syncthreads();
#pragma unroll
    for (int ks = 0; ks < 2; ks++) {
      bf16x8 af[4], bfr[4];
#pragma unroll
      for (int i = 0; i < 4; i++)
        af[i] = *(const bf16x8*)&As[wm + i * 16 + row16][ks * 32 + quad * 8];
#pragma unroll
      for (int j = 0; j < 4; j++)
        bfr[j] = *(const bf16x8*)&Bs[wn + j * 16 + row16][ks * 32 + quad * 8];
#pragma unroll
      for (int i = 0; i < 4; i++)
#pragma unroll
        for (int j = 0; j < 4; j++)
          acc[i][j] = __builtin_amdgcn_mfma_f32_16x16x32_bf16(af[i], bfr[j], acc[i][j], 0, 0, 0);
    }
    __syncthreads();
  }

#pragma unroll
  for (int i = 0; i < 4; i++) {
#pragma unroll
    for (int j = 0; j < 4; j++) {
#pragma unroll
      for (int r = 0; r < 4; r++) {
        int m = bm + wm + i * 16 + quad * 4 + r;
        int n = bn + wn + j * 16 + row16;
        float v = acc[i][j][r] + bias[n];
        v = 0.5f * v * (1.0f + erff(v * 0.70710678118f));
        outb[(size_t)m * FFD + n] = f2b(v);
      }
    }
  }
}

// ---------------- gemm64: 64x128 tile, reg-prefetched K-loop ----------------
// out fp32 = A(MxK) @ Bt(128xK)^T + bias[n] + resid[m*128+n]; grid (M/64, 1)
__global__ __launch_bounds__(256) void gemm64_kernel(
    const unsigned short* __restrict__ A, const unsigned short* __restrict__ Bt,
    int K, const float* __restrict__ bias, const float* __restrict__ resid,
    float* __restrict__ outf) {
  __shared__ unsigned short As[64][72];
  __shared__ unsigned short Bs[128][72];
  const int tid = threadIdx.x;
  const int wave = tid >> 6, lane = tid & 63;
  const int row16 = lane & 15, quad = lane >> 4;
  const int bm = blockIdx.x * 64;

  const int ar = tid >> 2, ag = (tid & 3) * 16;   // A: 64 rows x 64 cols per tile
  // B rows: tid>>2 and (tid>>2)+64 cover 0..127

  bf16x8 ra0, ra1, rb0, rb1, rb2, rb3;
  {
    const unsigned short* ap = &A[(size_t)(bm + ar) * K + ag];
    ra0 = *(const bf16x8*)ap; ra1 = *(const bf16x8*)(ap + 8);
    const unsigned short* bp = &Bt[(size_t)ar * K + ag];
    rb0 = *(const bf16x8*)bp; rb1 = *(const bf16x8*)(bp + 8);
    const unsigned short* bp2 = &Bt[(size_t)(ar + 64) * K + ag];
    rb2 = *(const bf16x8*)bp2; rb3 = *(const bf16x8*)(bp2 + 8);
  }

  const f32x4 zf = {0.f, 0.f, 0.f, 0.f};
  f32x4 acc[8];
#pragma unroll
  for (int j = 0; j < 8; j++) acc[j] = zf;

  for (int k0 = 0; k0 < K; k0 += 64) {
    __syncthreads();                       // prior iteration's frag reads done
    *(bf16x8*)&As[ar][ag] = ra0;  *(bf16x8*)&As[ar][ag + 8] = ra1;
    *(bf16x8*)&Bs[ar][ag] = rb0;  *(bf16x8*)&Bs[ar][ag + 8] = rb1;
    *(bf16x8*)&Bs[ar + 64][ag] = rb2; *(bf16x8*)&Bs[ar + 64][ag + 8] = rb3;
    __syncthreads();
    if (k0 + 64 < K) {                     // prefetch next tile; latency hides under MFMA
      const unsigned short* ap = &A[(size_t)(bm + ar) * K + k0 + 64 + ag];
      ra0 = *(const bf16x8*)ap; ra1 = *(const bf16x8*)(ap + 8);
      const unsigned short* bp = &Bt[(size_t)ar * K + k0 + 64 + ag];
      rb0 = *(const bf16x8*)bp; rb1 = *(const bf16x8*)(bp + 8);
      const unsigned short* bp2 = &Bt[(size_t)(ar + 64) * K + k0 + 64 + ag];
      rb2 = *(const bf16x8*)bp2; rb3 = *(const bf16x8*)(bp2 + 8);
    }
#pragma unroll
    for (int kc = 0; kc < 2; kc++) {
      bf16x8 af = *(const bf16x8*)&As[wave * 16 + row16][kc * 32 + quad * 8];
#pragma unroll
      for (int j = 0; j < 8; j++) {
        bf16x8 bfr = *(const bf16x8*)&Bs[j * 16 + row16][kc * 32 + quad * 8];
        acc[j] = __builtin_amdgcn_mfma_f32_16x16x32_bf16(af, bfr, acc[j], 0, 0, 0);
      }
    }
  }

#pragma unroll
  for (int j = 0; j < 8; j++) {
#pragma unroll
    for (int r = 0; r < 4; r++) {
      int m = bm + wave * 16 + quad * 4 + r;
      int n = j * 16 + row16;
      outf[(size_t)m * EMB + n] = acc[j][r] + bias[n] + resid[(size_t)m * EMB + n];
    }
  }
}

// ---------------- attention: one block per (b_local, h, qt); K/V direct from L2 ----------------
__global__ __launch_bounds__(256) void attn_kernel(
    const unsigned short* __restrict__ q, const unsigned short* __restrict__ k,
    const unsigned short* __restrict__ vt, const int* __restrict__ masks,
    unsigned short* __restrict__ att, int bc0) {
  __shared__ unsigned short Qs[64][136];
  __shared__ unsigned short Ps[64][232];
  __shared__ unsigned short mk[208];

  const int bx = blockIdx.x;           // 0..1023 within chunk
  const int bh = bx >> 2, qt = bx & 3;
  const int bl = bh >> 3, h = bh & 7;  // local batch, head
  const int bg = bc0 + bl;             // global batch
  const int b0 = bg >> 3, ag = bg & 7;
  const int tid = threadIdx.x;
  const int wave = tid >> 6, lane = tid & 63;
  const int row16 = lane & 15, quad = lane >> 4;
  const int q0 = wave * 16;

  const bf16x8 zv = {0, 0, 0, 0, 0, 0, 0, 0};
  const f32x4 zf = {0.f, 0.f, 0.f, 0.f};

  for (int t = tid; t < 208; t += 256)
    mk[t] = (t < SEQ) ? (unsigned short)(masks[(b0 * SEQ + t) * 8 + ag] != 0)
                      : (unsigned short)0;
  if (tid < 128) {  // zero P pad columns 208..223
    int r = tid >> 1, gcol = 208 + (tid & 1) * 8;
    *(bf16x8*)&Ps[r][gcol] = zv;
  }

  const unsigned short* qg = q + (size_t)bh * SEQ * EMB;
  const unsigned short* kg = k + (size_t)bh * SEQ * EMB;
  const unsigned short* vg = vt + (size_t)bh * EMB * SEQ;
  const float sc = 0.08838834764831845f;  // 1/sqrt(128) each for q and k
  unsigned short* ab = att + (size_t)bl * SEQ * (HEADS * EMB) + h * EMB;

  for (int i = tid; i < 64 * 16; i += 256) {
    int r = i >> 4, g = (i & 15) * 8;
    int gr = qt * 64 + r;
    bf16x8 v = (gr < SEQ) ? *(const bf16x8*)&qg[gr * EMB + g] : zv;
    *(bf16x8*)&Qs[r][g] = v;
  }
  __syncthreads();

  // S = (Q/s)(K/s)^T : 13 key-fragments of 16; K direct (L2-resident)
  f32x4 s[13];
#pragma unroll
  for (int kf = 0; kf < 13; kf++) s[kf] = zf;
#pragma unroll
  for (int e0 = 0; e0 < 4; e0++) {
    bf16x8 aq = *(const bf16x8*)&Qs[q0 + row16][e0 * 32 + quad * 8];
#pragma unroll
    for (int kf = 0; kf < 13; kf++) {
      int kr = kf * 16 + row16;
      kr = (kr < SEQ) ? kr : 0;  // clamped; masked below
      bf16x8 bk = *(const bf16x8*)&kg[kr * EMB + e0 * 32 + quad * 8];
      s[kf] = __builtin_amdgcn_mfma_f32_16x16x32_bf16(aq, bk, s[kf], 0, 0, 0);
    }
  }

  float kadd[13], kzero[13];
#pragma unroll
  for (int kf = 0; kf < 13; kf++) {
    bool mv = mk[kf * 16 + row16] != 0;
    kadd[kf] = mv ? 0.0f : -1e30f;
    kzero[kf] = mv ? 1.0f : 0.0f;
  }

#pragma unroll
  for (int r = 0; r < 4; r++) {
    int prow = q0 + quad * 4 + r;
    int grow = qt * 64 + prow;
    float qm = (grow < SEQ) ? (mk[grow] ? 1.0f : 0.0f) : 0.0f;
    float sv[13];
    float mx = -1e30f;
#pragma unroll
    for (int kf = 0; kf < 13; kf++) {
      float v = s[kf][r] * sc + kadd[kf];
      sv[kf] = v;
      mx = fmaxf(mx, v);
    }
#pragma unroll
    for (int d = 1; d < 16; d <<= 1) mx = fmaxf(mx, __shfl_xor(mx, d));
    float sum = 0.f;
#pragma unroll
    for (int kf = 0; kf < 13; kf++) {
      float e = __expf(sv[kf] - mx);
      sv[kf] = e;
      sum += e;
    }
#pragma unroll
    for (int d = 1; d < 16; d <<= 1) sum += __shfl_xor(sum, d);
    float inv = qm / sum;
#pragma unroll
    for (int kf = 0; kf < 13; kf++)
      Ps[prow][kf * 16 + row16] = f2b(sv[kf] * inv * kzero[kf]);
  }

  // O = P V ; V^T (e,t) direct; t-groups >= SEQ zeroed (P pad cols are 0)
  f32x4 o[8];
#pragma unroll
  for (int n = 0; n < 8; n++) o[n] = zf;
#pragma unroll
  for (int ks = 0; ks < 7; ks++) {
    bf16x8 ap = *(const bf16x8*)&Ps[q0 + row16][ks * 32 + quad * 8];
    int t0 = ks * 32 + quad * 8;
#pragma unroll
    for (int n = 0; n < 8; n++) {
      int er = n * 16 + row16;
      bf16x8 bv = (t0 < SEQ) ? *(const bf16x8*)&vg[er * SEQ + t0] : zv;
      o[n] = __builtin_amdgcn_mfma_f32_16x16x32_bf16(ap, bv, o[n], 0, 0, 0);
    }
  }

#pragma unroll
  for (int n = 0; n < 8; n++) {
#pragma unroll
    for (int r = 0; r < 4; r++) {
      int grow = qt * 64 + q0 + quad * 4 + r;
      if (grow < SEQ)
        ab[(size_t)grow * (HEADS * EMB) + n * 16 + row16] = f2b(o[n][r]);
    }
  }
}

// ---------------- LayerNorm over last dim 128; one wave per token ----------------
__global__ __launch_bounds__(256) void ln_kernel(const float* __restrict__ in,
    const float* __restrict__ w, const float* __restrict__ b,
    float* __restrict__ outf, unsigned short* __restrict__ outb) {
  int wave = threadIdx.x >> 6, lane = threadIdx.x & 63;
  int tokidx = blockIdx.x * 4 + wave;
  const float* row = in + (size_t)tokidx * EMB;
  float2 v = *(const float2*)(row + lane * 2);
  float sum = v.x + v.y;
  float sq = v.x * v.x + v.y * v.y;
#pragma unroll
  for (int d = 1; d < 64; d <<= 1) {
    sum += __shfl_xor(sum, d);
    sq += __shfl_xor(sq, d);
  }
  float mean = sum * (1.0f / 128.0f);
  float var = sq * (1.0f / 128.0f) - mean * mean;
  float rstd = rsqrtf(var + 1e-5f);
  float2 wv = *(const float2*)(w + lane * 2);
  float2 bv = *(const float2*)(b + lane * 2);
  float2 ov;
  ov.x = (v.x - mean) * rstd * wv.x + bv.x;
  ov.y = (v.y - mean) * rstd * wv.y + bv.y;
  *(float2*)(outf + (size_t)tokidx * EMB + lane * 2) = ov;
  if (outb) {
    outb[(size_t)tokidx * EMB + lane * 2] = f2b(ov.x);
    outb[(size_t)tokidx * EMB + lane * 2 + 1] = f2b(ov.y);
  }
}

extern "C" void kernel_launch(void* const* d_in, const int* in_sizes, int n_in,
                              void* d_out, int out_size, void* d_ws, size_t ws_size,
                              hipStream_t stream) {
  const float* x    = (const float*)d_in[0];
  const float* pos  = (const float*)d_in[1];
  const float* Wq   = (const float*)d_in[2];
  const float* Wk   = (const float*)d_in[3];
  const float* Wv   = (const float*)d_in[4];
  const float* Wu   = (const float*)d_in[5];
  const float* bu   = (const float*)d_in[6];
  const float* ln1w = (const float*)d_in[7];
  const float* ln1b = (const float*)d_in[8];
  const float* W1   = (const float*)d_in[9];
  const float* b1   = (const float*)d_in[10];
  const float* W2   = (const float*)d_in[11];
  const float* b2   = (const float*)d_in[12];
  const float* ln2w = (const float*)d_in[13];
  const float* ln2b = (const float*)d_in[14];
  const int* masks  = (const int*)d_in[15];
  float* out = (float*)d_out;
  (void)in_sizes; (void)n_in; (void)out_size;

  char* ws = (char*)d_ws;
  // common region
  unsigned short* wqkv = (unsigned short*)(ws + 0);        //   786,432
  unsigned short* wut  = (unsigned short*)(ws + 786432);   //   262,144
  unsigned short* w1t  = (unsigned short*)(ws + 1048576);  //   131,072
  unsigned short* w2t  = (unsigned short*)(ws + 1179648);  //   131,072 -> 1,310,720
  float* xpos          = (float*)(ws + 1310720);           // 13,107,200 -> 14,417,920
  unsigned short* xb   = (unsigned short*)(ws + 14417920); //  6,553,600 -> 20,971,520

  prep_kernel<<<3200, 256, 0, stream>>>(x, pos, xpos, xb);
  wconv_all<<<2560, 256, 0, stream>>>(Wq, Wk, Wv, Wu, W1, W2, wqkv, wut, w1t, w2t);

  const size_t BIG_NEED = 112721920ULL;
  if (ws_size >= BIG_NEED) {
    // BIG layout: att full-batch; Wu hoisted to one (400,1) dispatch
    unsigned short* qc   = (unsigned short*)(ws + 20971520); // 13.1 MB
    unsigned short* kcb  = (unsigned short*)(ws + 34078720); // 13.1 MB
    unsigned short* vcb  = (unsigned short*)(ws + 47185920); // 13.1 MB
    unsigned short* attf = (unsigned short*)(ws + 60293120); // 52.4 MB -> 112,721,920
    float* t1            = (float*)(ws + 20971520);          // alias qc (dead after loop)
    float* yf            = (float*)(ws + 60293120);          // alias attf (dead after Wu)
    unsigned short* yb   = (unsigned short*)(ws + 73400320);
    unsigned short* g    = (unsigned short*)(ws + 79953920); // 26.2 MB -> 106,168,320

    for (int c = 0; c < NCHUNK; c++) {
      const unsigned short* xbc = xb + (size_t)c * CHUNK * SEQ * EMB;
      gemm_qkv<<<dim3(50, 24), 256, 0, stream>>>(xbc, wqkv, qc, kcb, vcb);
      attn_kernel<<<1024, 256, 0, stream>>>(qc, kcb, vcb, masks,
          attf + (size_t)c * CHUNK * SEQ * (HEADS * EMB), c * CHUNK);
    }
    gemm64_kernel<<<400, 256, 0, stream>>>(attf, wut, 1024, bu, xpos, t1);
    ln_kernel<<<6400, 256, 0, stream>>>(t1, ln1w, ln1b, yf, yb);
    gemm_ff1<<<dim3(200, 4), 256, 0, stream>>>(yb, w1t, b1, g);
    gemm64_kernel<<<400, 256, 0, stream>>>(g, w2t, 512, b2, yf, t1);
    ln_kernel<<<6400, 256, 0, stream>>>(t1, ln2w, ln2b, out, nullptr);
  } else {
    // SMALL layout (proven 86.5 MB envelope): per-chunk Wu
    float* t1            = (float*)(ws + 20971520);          // 13.1 MB
    unsigned short* qc   = (unsigned short*)(ws + 34078720);
    unsigned short* kcb  = (unsigned short*)(ws + 47185920);
    unsigned short* vcb  = (unsigned short*)(ws + 60293120);
    unsigned short* attc = (unsigned short*)(ws + 73400320); // -> 86,507,520
    float* yf            = (float*)(ws + 34078720);          // alias qc (dead after loop)
    unsigned short* yb   = (unsigned short*)(ws + 47185920);
    unsigned short* g    = (unsigned short*)(ws + 53739520); // -> 79,953,920

    for (int c = 0; c < NCHUNK; c++) {
      const unsigned short* xbc = xb + (size_t)c * CHUNK * SEQ * EMB;
      gemm_qkv<<<dim3(50, 24), 256, 0, stream>>>(xbc, wqkv, qc, kcb, vcb);
      attn_kernel<<<1024, 256, 0, stream>>>(qc, kcb, vcb, masks, attc, c * CHUNK);
      gemm64_kernel<<<100, 256, 0, stream>>>(attc, wut, 1024, bu,
          xpos + (size_t)c * CHUNK * SEQ * EMB, t1 + (size_t)c * CHUNK * SEQ * EMB);
    }
    ln_kernel<<<6400, 256, 0, stream>>>(t1, ln1w, ln1b, yf, yb);
    gemm_ff1<<<dim3(200, 4), 256, 0, stream>>>(yb, w1t, b1, g);
    gemm64_kernel<<<400, 256, 0, stream>>>(g, w2t, 512, b2, yf, t1);
    ln_kernel<<<6400, 256, 0, stream>>>(t1, ln2w, ln2b, out, nullptr);
  }
}

// Round 11
// 493.751 us; speedup vs baseline: 1.8892x; 1.0204x over previous
//
#include <hip/hip_runtime.h>
#include <math.h>

#define EMB 128
#define HEADS 8
#define SEQ 200
#define BATCH 128
#define FFD 512
#define CHUNK 32          // batches per chunk
#define NCHUNK 4

typedef __attribute__((ext_vector_type(8))) short bf16x8;
typedef __attribute__((ext_vector_type(4))) float f32x4;

__device__ __forceinline__ unsigned short f2b(float f) {
  union { float f; unsigned int u; } v; v.f = f;
  unsigned int u = v.u;
  return (unsigned short)((u + 0x7fffu + ((u >> 16) & 1u)) >> 16);
}

// ---------------- prep: x + pos_emb -> fp32 residual + bf16 copy ----------------
__global__ __launch_bounds__(256) void prep_kernel(const float* __restrict__ x,
    const float* __restrict__ pos, float* __restrict__ xpos,
    unsigned short* __restrict__ xb) {
  int idx = blockIdx.x * 256 + threadIdx.x;
  int base = idx * 4;
  int tok = base >> 7;
  int t = tok % SEQ;
  int e = base & 127;
  float4 xv = *(const float4*)(x + base);
  float4 pv = *(const float4*)(pos + t * EMB + e);
  float4 r;
  r.x = xv.x + pv.x; r.y = xv.y + pv.y; r.z = xv.z + pv.z; r.w = xv.w + pv.w;
  *(float4*)(xpos + base) = r;
  ushort4 o;
  o.x = f2b(r.x); o.y = f2b(r.y); o.z = f2b(r.z); o.w = f2b(r.w);
  *(ushort4*)(xb + base) = o;
}

// ---------------- all six weights fp32 -> bf16 transposed, one dispatch ----------------
__global__ __launch_bounds__(256) void wconv_all(
    const float* __restrict__ Wq, const float* __restrict__ Wk,
    const float* __restrict__ Wv, const float* __restrict__ Wu,
    const float* __restrict__ W1, const float* __restrict__ W2,
    unsigned short* __restrict__ wqkv, unsigned short* __restrict__ wut,
    unsigned short* __restrict__ w1t, unsigned short* __restrict__ w2t) {
  int idx = blockIdx.x * 256 + threadIdx.x;   // 0 .. 655359
  if (idx < 393216) {                          // Wq/Wk/Wv: 3 x (128x1024)
    int t = idx / 131072, r = idx - t * 131072;  // r = k*1024 + n
    int k = r >> 10, n = r & 1023;
    const float* W = (t == 0) ? Wq : (t == 1) ? Wk : Wv;
    wqkv[(size_t)(t * 1024 + n) * 128 + k] = f2b(W[r]);
  } else if (idx < 524288) {                   // Wu: 1024x128, r = k*128 + n
    int r = idx - 393216; int k = r >> 7, n = r & 127;
    wut[(size_t)n * 1024 + k] = f2b(Wu[r]);
  } else if (idx < 589824) {                   // W1: 128x512, r = k*512 + n
    int r = idx - 524288; int k = r >> 9, n = r & 511;
    w1t[(size_t)n * 128 + k] = f2b(W1[r]);
  } else {                                     // W2: 512x128, r = k*128 + n
    int r = idx - 589824; int k = r >> 7, n = r & 127;
    w2t[(size_t)n * 512 + k] = f2b(W2[r]);
  }
}

// ---------------- merged QKV GEMM per chunk: grid (50, 24), K=128 ----------------
// Register-prefetched 2-tile K loop (gemm64 pattern).
__global__ __launch_bounds__(256) void gemm_qkv(
    const unsigned short* __restrict__ A, const unsigned short* __restrict__ Bt,
    unsigned short* __restrict__ qc, unsigned short* __restrict__ kc,
    unsigned short* __restrict__ vc) {
  __shared__ unsigned short As[128][72];
  __shared__ unsigned short Bs[128][72];
  const int K = 128;
  const int tid = threadIdx.x;
  const int bm = blockIdx.x * 128;
  const int bn = blockIdx.y * 128;
  const int wave = tid >> 6, lane = tid & 63;
  const int wm = (wave >> 1) * 64, wn = (wave & 1) * 64;
  const int row16 = lane & 15, quad = lane >> 4;

  const f32x4 zf = {0.f, 0.f, 0.f, 0.f};
  f32x4 acc[4][4];
#pragma unroll
  for (int i = 0; i < 4; i++)
#pragma unroll
    for (int j = 0; j < 4; j++) acc[i][j] = zf;

  bf16x8 ra[4], rb[4];
#pragma unroll
  for (int u = 0; u < 4; u++) {
    int i = tid + u * 256; int r = i >> 3, g = (i & 7) * 8;
    ra[u] = *(const bf16x8*)&A[(size_t)(bm + r) * K + g];
    rb[u] = *(const bf16x8*)&Bt[(size_t)(bn + r) * K + g];
  }

  for (int k0 = 0; k0 < 2; k0++) {
    if (k0) __syncthreads();               // protect LDS reuse from prior reads
#pragma unroll
    for (int u = 0; u < 4; u++) {
      int i = tid + u * 256; int r = i >> 3, g = (i & 7) * 8;
      *(bf16x8*)&As[r][g] = ra[u];
      *(bf16x8*)&Bs[r][g] = rb[u];
    }
    __syncthreads();
    if (k0 == 0) {                         // prefetch tile 1 under tile 0's MFMAs
#pragma unroll
      for (int u = 0; u < 4; u++) {
        int i = tid + u * 256; int r = i >> 3, g = (i & 7) * 8;
        ra[u] = *(const bf16x8*)&A[(size_t)(bm + r) * K + 64 + g];
        rb[u] = *(const bf16x8*)&Bt[(size_t)(bn + r) * K + 64 + g];
      }
    }
#pragma unroll
    for (int ks = 0; ks < 2; ks++) {
      bf16x8 af[4], bfr[4];
#pragma unroll
      for (int i = 0; i < 4; i++)
        af[i] = *(const bf16x8*)&As[wm + i * 16 + row16][ks * 32 + quad * 8];
#pragma unroll
      for (int j = 0; j < 4; j++)
        bfr[j] = *(const bf16x8*)&Bs[wn + j * 16 + row16][ks * 32 + quad * 8];
#pragma unroll
      for (int i = 0; i < 4; i++)
#pragma unroll
        for (int j = 0; j < 4; j++)
          acc[i][j] = __builtin_amdgcn_mfma_f32_16x16x32_bf16(af[i], bfr[j], acc[i][j], 0, 0, 0);
    }
  }

  const int tensor = blockIdx.y >> 3, h = blockIdx.y & 7;
  unsigned short* outp = (tensor == 0) ? qc : (tensor == 1) ? kc : vc;
#pragma unroll
  for (int i = 0; i < 4; i++) {
#pragma unroll
    for (int j = 0; j < 4; j++) {
#pragma unroll
      for (int r = 0; r < 4; r++) {
        int m = bm + wm + i * 16 + quad * 4 + r;
        int n = wn + j * 16 + row16;          // e within head
        float c = acc[i][j][r];
        int bb = m / SEQ, t = m - bb * SEQ;
        if (tensor < 2)
          outp[(size_t)((bb * HEADS + h) * SEQ + t) * EMB + n] = f2b(c);
        else
          outp[(size_t)((bb * HEADS + h) * EMB + n) * SEQ + t] = f2b(c);
      }
    }
  }
}

// ---------------- FF1 GEMM: out bf16 = gelu(C + bias), grid (200,4), K=128 ----------------
// Register-prefetched 2-tile K loop.
__global__ __launch_bounds__(256) void gemm_ff1(
    const unsigned short* __restrict__ A, const unsigned short* __restrict__ Bt,
    const float* __restrict__ bias, unsigned short* __restrict__ outb) {
  __shared__ unsigned short As[128][72];
  __shared__ unsigned short Bs[128][72];
  const int K = 128;
  const int tid = threadIdx.x;
  const int bm = blockIdx.x * 128;
  const int bn = blockIdx.y * 128;
  const int wave = tid >> 6, lane = tid & 63;
  const int wm = (wave >> 1) * 64, wn = (wave & 1) * 64;
  const int row16 = lane & 15, quad = lane >> 4;

  const f32x4 zf = {0.f, 0.f, 0.f, 0.f};
  f32x4 acc[4][4];
#pragma unroll
  for (int i = 0; i < 4; i++)
#pragma unroll
    for (int j = 0; j < 4; j++) acc[i][j] = zf;

  bf16x8 ra[4], rb[4];
#pragma unroll
  for (int u = 0; u < 4; u++) {
    int i = tid + u * 256; int r = i >> 3, g = (i & 7) * 8;
    ra[u] = *(const bf16x8*)&A[(size_t)(bm + r) * K + g];
    rb[u] = *(const bf16x8*)&Bt[(size_t)(bn + r) * K + g];
  }

  for (int k0 = 0; k0 < 2; k0++) {
    if (k0) __syncthreads();
#pragma unroll
    for (int u = 0; u < 4; u++) {
      int i = tid + u * 256; int r = i >> 3, g = (i & 7) * 8;
      *(bf16x8*)&As[r][g] = ra[u];
      *(bf16x8*)&Bs[r][g] = rb[u];
    }
    __syncthreads();
    if (k0 == 0) {
#pragma unroll
      for (int u = 0; u < 4; u++) {
        int i = tid + u * 256; int r = i >> 3, g = (i & 7) * 8;
        ra[u] = *(const bf16x8*)&A[(size_t)(bm + r) * K + 64 + g];
        rb[u] = *(const bf16x8*)&Bt[(size_t)(bn + r) * K + 64 + g];
      }
    }
#pragma unroll
    for (int ks = 0; ks < 2; ks++) {
      bf16x8 af[4], bfr[4];
#pragma unroll
      for (int i = 0; i < 4; i++)
        af[i] = *(const bf16x8*)&As[wm + i * 16 + row16][ks * 32 + quad * 8];
#pragma unroll
      for (int j = 0; j < 4; j++)
        bfr[j] = *(const bf16x8*)&Bs[wn + j * 16 + row16][ks * 32 + quad * 8];
#pragma unroll
      for (int i = 0; i < 4; i++)
#pragma unroll
        for (int j = 0; j < 4; j++)
          acc[i][j] = __builtin_amdgcn_mfma_f32_16x16x32_bf16(af[i], bfr[j], acc[i][j], 0, 0, 0);
    }
  }

#pragma unroll
  for (int i = 0; i < 4; i++) {
#pragma unroll
    for (int j = 0; j < 4; j++) {
#pragma unroll
      for (int r = 0; r < 4; r++) {
        int m = bm + wm + i * 16 + quad * 4 + r;
        int n = bn + wn + j * 16 + row16;
        float v = acc[i][j][r] + bias[n];
        v = 0.5f * v * (1.0f + erff(v * 0.70710678118f));
        outb[(size_t)m * FFD + n] = f2b(v);
      }
    }
  }
}

// ---------------- gemm64: 64x128 tile, reg-prefetched K-loop ----------------
// out fp32 = A(MxK) @ Bt(128xK)^T + bias[n] + resid[m*128+n]; grid (M/64, 1)
__global__ __launch_bounds__(256) void gemm64_kernel(
    const unsigned short* __restrict__ A, const unsigned short* __restrict__ Bt,
    int K, const float* __restrict__ bias, const float* __restrict__ resid,
    float* __restrict__ outf) {
  __shared__ unsigned short As[64][72];
  __shared__ unsigned short Bs[128][72];
  const int tid = threadIdx.x;
  const int wave = tid >> 6, lane = tid & 63;
  const int row16 = lane & 15, quad = lane >> 4;
  const int bm = blockIdx.x * 64;

  const int ar = tid >> 2, ag = (tid & 3) * 16;   // A: 64 rows x 64 cols per tile

  bf16x8 ra0, ra1, rb0, rb1, rb2, rb3;
  {
    const unsigned short* ap = &A[(size_t)(bm + ar) * K + ag];
    ra0 = *(const bf16x8*)ap; ra1 = *(const bf16x8*)(ap + 8);
    const unsigned short* bp = &Bt[(size_t)ar * K + ag];
    rb0 = *(const bf16x8*)bp; rb1 = *(const bf16x8*)(bp + 8);
    const unsigned short* bp2 = &Bt[(size_t)(ar + 64) * K + ag];
    rb2 = *(const bf16x8*)bp2; rb3 = *(const bf16x8*)(bp2 + 8);
  }

  const f32x4 zf = {0.f, 0.f, 0.f, 0.f};
  f32x4 acc[8];
#pragma unroll
  for (int j = 0; j < 8; j++) acc[j] = zf;

  for (int k0 = 0; k0 < K; k0 += 64) {
    __syncthreads();                       // prior iteration's frag reads done
    *(bf16x8*)&As[ar][ag] = ra0;  *(bf16x8*)&As[ar][ag + 8] = ra1;
    *(bf16x8*)&Bs[ar][ag] = rb0;  *(bf16x8*)&Bs[ar][ag + 8] = rb1;
    *(bf16x8*)&Bs[ar + 64][ag] = rb2; *(bf16x8*)&Bs[ar + 64][ag + 8] = rb3;
    __syncthreads();
    if (k0 + 64 < K) {                     // prefetch next tile; latency hides under MFMA
      const unsigned short* ap = &A[(size_t)(bm + ar) * K + k0 + 64 + ag];
      ra0 = *(const bf16x8*)ap; ra1 = *(const bf16x8*)(ap + 8);
      const unsigned short* bp = &Bt[(size_t)ar * K + k0 + 64 + ag];
      rb0 = *(const bf16x8*)bp; rb1 = *(const bf16x8*)(bp + 8);
      const unsigned short* bp2 = &Bt[(size_t)(ar + 64) * K + k0 + 64 + ag];
      rb2 = *(const bf16x8*)bp2; rb3 = *(const bf16x8*)(bp2 + 8);
    }
#pragma unroll
    for (int kc = 0; kc < 2; kc++) {
      bf16x8 af = *(const bf16x8*)&As[wave * 16 + row16][kc * 32 + quad * 8];
#pragma unroll
      for (int j = 0; j < 8; j++) {
        bf16x8 bfr = *(const bf16x8*)&Bs[j * 16 + row16][kc * 32 + quad * 8];
        acc[j] = __builtin_amdgcn_mfma_f32_16x16x32_bf16(af, bfr, acc[j], 0, 0, 0);
      }
    }
  }

#pragma unroll
  for (int j = 0; j < 8; j++) {
#pragma unroll
    for (int r = 0; r < 4; r++) {
      int m = bm + wave * 16 + quad * 4 + r;
      int n = j * 16 + row16;
      outf[(size_t)m * EMB + n] = acc[j][r] + bias[n] + resid[(size_t)m * EMB + n];
    }
  }
}

// ---------------- attention v3: one block per (b_local, h, qt) ----------------
// Q fragments direct from global (no LDS staging — zero cross-wave reuse).
// LDS = Ps + mask only (30.1 KB -> 5 blocks/CU). Single barrier.
__global__ __launch_bounds__(256) void attn_kernel(
    const unsigned short* __restrict__ q, const unsigned short* __restrict__ k,
    const unsigned short* __restrict__ vt, const int* __restrict__ masks,
    unsigned short* __restrict__ att, int bc0) {
  __shared__ unsigned short Ps[64][232];
  __shared__ unsigned short mk[208];

  const int bx = blockIdx.x;           // 0..1023 within chunk
  const int bh = bx >> 2, qt = bx & 3;
  const int bl = bh >> 3, h = bh & 7;  // local batch, head
  const int bg = bc0 + bl;             // global batch
  const int b0 = bg >> 3, ag = bg & 7;
  const int tid = threadIdx.x;
  const int wave = tid >> 6, lane = tid & 63;
  const int row16 = lane & 15, quad = lane >> 4;
  const int q0 = wave * 16;

  const bf16x8 zv = {0, 0, 0, 0, 0, 0, 0, 0};
  const f32x4 zf = {0.f, 0.f, 0.f, 0.f};

  for (int t = tid; t < 208; t += 256)
    mk[t] = (t < SEQ) ? (unsigned short)(masks[(b0 * SEQ + t) * 8 + ag] != 0)
                      : (unsigned short)0;
  if (tid < 128) {  // zero P pad columns 208..223 (read by all waves in PV)
    int r = tid >> 1, gcol = 208 + (tid & 1) * 8;
    *(bf16x8*)&Ps[r][gcol] = zv;
  }
  __syncthreads();

  const unsigned short* qg = q + (size_t)bh * SEQ * EMB;
  const unsigned short* kg = k + (size_t)bh * SEQ * EMB;
  const unsigned short* vg = vt + (size_t)bh * EMB * SEQ;
  const float sc = 0.08838834764831845f;  // 1/sqrt(128) each for q and k
  unsigned short* ab = att + (size_t)bl * SEQ * (HEADS * EMB) + h * EMB;

  // Q fragments: row gr = qt*64 + q0 + row16, cols e0*32+quad*8 (16B aligned)
  const int gr = qt * 64 + q0 + row16;
  bf16x8 aqv[4];
#pragma unroll
  for (int e0 = 0; e0 < 4; e0++)
    aqv[e0] = (gr < SEQ) ? *(const bf16x8*)&qg[gr * EMB + e0 * 32 + quad * 8] : zv;

  // S = (Q/s)(K/s)^T : 13 key-fragments of 16; K direct (L2-resident)
  f32x4 s[13];
#pragma unroll
  for (int kf = 0; kf < 13; kf++) s[kf] = zf;
#pragma unroll
  for (int e0 = 0; e0 < 4; e0++) {
#pragma unroll
    for (int kf = 0; kf < 13; kf++) {
      int kr = kf * 16 + row16;
      kr = (kr < SEQ) ? kr : 0;  // clamped; masked below
      bf16x8 bk = *(const bf16x8*)&kg[kr * EMB + e0 * 32 + quad * 8];
      s[kf] = __builtin_amdgcn_mfma_f32_16x16x32_bf16(aqv[e0], bk, s[kf], 0, 0, 0);
    }
  }

  float kadd[13], kzero[13];
#pragma unroll
  for (int kf = 0; kf < 13; kf++) {
    bool mv = mk[kf * 16 + row16] != 0;
    kadd[kf] = mv ? 0.0f : -1e30f;
    kzero[kf] = mv ? 1.0f : 0.0f;
  }

#pragma unroll
  for (int r = 0; r < 4; r++) {
    int prow = q0 + quad * 4 + r;
    int grow = qt * 64 + prow;
    float qm = (grow < SEQ) ? (mk[grow] ? 1.0f : 0.0f) : 0.0f;
    float sv[13];
    float mx = -1e30f;
#pragma unroll
    for (int kf = 0; kf < 13; kf++) {
      float v = s[kf][r] * sc + kadd[kf];
      sv[kf] = v;
      mx = fmaxf(mx, v);
    }
#pragma unroll
    for (int d = 1; d < 16; d <<= 1) mx = fmaxf(mx, __shfl_xor(mx, d));
    float sum = 0.f;
#pragma unroll
    for (int kf = 0; kf < 13; kf++) {
      float e = __expf(sv[kf] - mx);
      sv[kf] = e;
      sum += e;
    }
#pragma unroll
    for (int d = 1; d < 16; d <<= 1) sum += __shfl_xor(sum, d);
    float inv = qm / sum;
#pragma unroll
    for (int kf = 0; kf < 13; kf++)
      Ps[prow][kf * 16 + row16] = f2b(sv[kf] * inv * kzero[kf]);
  }
  // P write->read is wave-local (wave writes rows q0..q0+15, reads the same): no barrier

  // O = P V ; V^T (e,t) direct; t-groups >= SEQ zeroed (P pad cols are 0)
  f32x4 o[8];
#pragma unroll
  for (int n = 0; n < 8; n++) o[n] = zf;
#pragma unroll
  for (int ks = 0; ks < 7; ks++) {
    bf16x8 ap = *(const bf16x8*)&Ps[q0 + row16][ks * 32 + quad * 8];
    int t0 = ks * 32 + quad * 8;
#pragma unroll
    for (int n = 0; n < 8; n++) {
      int er = n * 16 + row16;
      bf16x8 bv = (t0 < SEQ) ? *(const bf16x8*)&vg[er * SEQ + t0] : zv;
      o[n] = __builtin_amdgcn_mfma_f32_16x16x32_bf16(ap, bv, o[n], 0, 0, 0);
    }
  }

#pragma unroll
  for (int n = 0; n < 8; n++) {
#pragma unroll
    for (int r = 0; r < 4; r++) {
      int grow = qt * 64 + q0 + quad * 4 + r;
      if (grow < SEQ)
        ab[(size_t)grow * (HEADS * EMB) + n * 16 + row16] = f2b(o[n][r]);
    }
  }
}

// ---------------- LayerNorm over last dim 128; one wave per token ----------------
__global__ __launch_bounds__(256) void ln_kernel(const float* __restrict__ in,
    const float* __restrict__ w, const float* __restrict__ b,
    float* __restrict__ outf, unsigned short* __restrict__ outb) {
  int wave = threadIdx.x >> 6, lane = threadIdx.x & 63;
  int tokidx = blockIdx.x * 4 + wave;
  const float* row = in + (size_t)tokidx * EMB;
  float2 v = *(const float2*)(row + lane * 2);
  float sum = v.x + v.y;
  float sq = v.x * v.x + v.y * v.y;
#pragma unroll
  for (int d = 1; d < 64; d <<= 1) {
    sum += __shfl_xor(sum, d);
    sq += __shfl_xor(sq, d);
  }
  float mean = sum * (1.0f / 128.0f);
  float var = sq * (1.0f / 128.0f) - mean * mean;
  float rstd = rsqrtf(var + 1e-5f);
  float2 wv = *(const float2*)(w + lane * 2);
  float2 bv = *(const float2*)(b + lane * 2);
  float2 ov;
  ov.x = (v.x - mean) * rstd * wv.x + bv.x;
  ov.y = (v.y - mean) * rstd * wv.y + bv.y;
  *(float2*)(outf + (size_t)tokidx * EMB + lane * 2) = ov;
  if (outb) {
    outb[(size_t)tokidx * EMB + lane * 2] = f2b(ov.x);
    outb[(size_t)tokidx * EMB + lane * 2 + 1] = f2b(ov.y);
  }
}

extern "C" void kernel_launch(void* const* d_in, const int* in_sizes, int n_in,
                              void* d_out, int out_size, void* d_ws, size_t ws_size,
                              hipStream_t stream) {
  const float* x    = (const float*)d_in[0];
  const float* pos  = (const float*)d_in[1];
  const float* Wq   = (const float*)d_in[2];
  const float* Wk   = (const float*)d_in[3];
  const float* Wv   = (const float*)d_in[4];
  const float* Wu   = (const float*)d_in[5];
  const float* bu   = (const float*)d_in[6];
  const float* ln1w = (const float*)d_in[7];
  const float* ln1b = (const float*)d_in[8];
  const float* W1   = (const float*)d_in[9];
  const float* b1   = (const float*)d_in[10];
  const float* W2   = (const float*)d_in[11];
  const float* b2   = (const float*)d_in[12];
  const float* ln2w = (const float*)d_in[13];
  const float* ln2b = (const float*)d_in[14];
  const int* masks  = (const int*)d_in[15];
  float* out = (float*)d_out;
  (void)in_sizes; (void)n_in; (void)out_size;

  char* ws = (char*)d_ws;
  // common region
  unsigned short* wqkv = (unsigned short*)(ws + 0);        //   786,432
  unsigned short* wut  = (unsigned short*)(ws + 786432);   //   262,144
  unsigned short* w1t  = (unsigned short*)(ws + 1048576);  //   131,072
  unsigned short* w2t  = (unsigned short*)(ws + 1179648);  //   131,072 -> 1,310,720
  float* xpos          = (float*)(ws + 1310720);           // 13,107,200 -> 14,417,920
  unsigned short* xb   = (unsigned short*)(ws + 14417920); //  6,553,600 -> 20,971,520

  prep_kernel<<<3200, 256, 0, stream>>>(x, pos, xpos, xb);
  wconv_all<<<2560, 256, 0, stream>>>(Wq, Wk, Wv, Wu, W1, W2, wqkv, wut, w1t, w2t);

  const size_t BIG_NEED = 112721920ULL;
  if (ws_size >= BIG_NEED) {
    // BIG layout: att full-batch; Wu hoisted to one (400,1) dispatch
    unsigned short* qc   = (unsigned short*)(ws + 20971520); // 13.1 MB
    unsigned short* kcb  = (unsigned short*)(ws + 34078720); // 13.1 MB
    unsigned short* vcb  = (unsigned short*)(ws + 47185920); // 13.1 MB
    unsigned short* attf = (unsigned short*)(ws + 60293120); // 52.4 MB -> 112,721,920
    float* t1            = (float*)(ws + 20971520);          // alias qc (dead after loop)
    float* yf            = (float*)(ws + 60293120);          // alias attf (dead after Wu)
    unsigned short* yb   = (unsigned short*)(ws + 73400320);
    unsigned short* g    = (unsigned short*)(ws + 79953920); // 26.2 MB -> 106,168,320

    for (int c = 0; c < NCHUNK; c++) {
      const unsigned short* xbc = xb + (size_t)c * CHUNK * SEQ * EMB;
      gemm_qkv<<<dim3(50, 24), 256, 0, stream>>>(xbc, wqkv, qc, kcb, vcb);
      attn_kernel<<<1024, 256, 0, stream>>>(qc, kcb, vcb, masks,
          attf + (size_t)c * CHUNK * SEQ * (HEADS * EMB), c * CHUNK);
    }
    gemm64_kernel<<<400, 256, 0, stream>>>(attf, wut, 1024, bu, xpos, t1);
    ln_kernel<<<6400, 256, 0, stream>>>(t1, ln1w, ln1b, yf, yb);
    gemm_ff1<<<dim3(200, 4), 256, 0, stream>>>(yb, w1t, b1, g);
    gemm64_kernel<<<400, 256, 0, stream>>>(g, w2t, 512, b2, yf, t1);
    ln_kernel<<<6400, 256, 0, stream>>>(t1, ln2w, ln2b, out, nullptr);
  } else {
    // SMALL layout (proven 86.5 MB envelope): per-chunk Wu
    float* t1            = (float*)(ws + 20971520);          // 13.1 MB
    unsigned short* qc   = (unsigned short*)(ws + 34078720);
    unsigned short* kcb  = (unsigned short*)(ws + 47185920);
    unsigned short* vcb  = (unsigned short*)(ws + 60293120);
    unsigned short* attc = (unsigned short*)(ws + 73400320); // -> 86,507,520
    float* yf            = (float*)(ws + 34078720);          // alias qc (dead after loop)
    unsigned short* yb   = (unsigned short*)(ws + 47185920);
    unsigned short* g    = (unsigned short*)(ws + 53739520); // -> 79,953,920

    for (int c = 0; c < NCHUNK; c++) {
      const unsigned short* xbc = xb + (size_t)c * CHUNK * SEQ * EMB;
      gemm_qkv<<<dim3(50, 24), 256, 0, stream>>>(xbc, wqkv, qc, kcb, vcb);
      attn_kernel<<<1024, 256, 0, stream>>>(qc, kcb, vcb, masks, attc, c * CHUNK);
      gemm64_kernel<<<100, 256, 0, stream>>>(attc, wut, 1024, bu,
          xpos + (size_t)c * CHUNK * SEQ * EMB, t1 + (size_t)c * CHUNK * SEQ * EMB);
    }
    ln_kernel<<<6400, 256, 0, stream>>>(t1, ln1w, ln1b, yf, yb);
    gemm_ff1<<<dim3(200, 4), 256, 0, stream>>>(yb, w1t, b1, g);
    gemm64_kernel<<<400, 256, 0, stream>>>(g, w2t, 512, b2, yf, t1);
    ln_kernel<<<6400, 256, 0, stream>>>(t1, ln2w, ln2b, out, nullptr);
  }
}